// Round 11
// baseline (213.949 us; speedup 1.0000x reference)
//
#include <hip/hip_runtime.h>
#include <stdint.h>

// ---------------- problem dims ----------------
#define B_DIM 64
#define P_DIM 225
#define K_DIM 16
#define D_DIM 640
#define M_REAL (B_DIM * P_DIM)   // 14400 query rows
#define N_REAL (K_DIM * P_DIM)   // 3600 reference rows

// ---------------- GEMM tiling (round-2 proven config) ----------------
#define BM 128
#define BN 128
#define MTILES 113               // ceil(14400/128) -> Mpad 14464
#define NTILES 29                // ceil(3600/128)  -> Npad 3712
#define MPAD (MTILES * BM)
#define NPAD (NTILES * BN)
#define MCHUNK 15                // ceil(MTILES/8) per-XCD bm groups

typedef float f32x4 __attribute__((ext_vector_type(4)));
typedef int   i32x4 __attribute__((ext_vector_type(4)));
typedef int   i32x8 __attribute__((ext_vector_type(8)));

// ---------------- helpers ----------------
// monotone float -> uint key (order-preserving), for atomicMax on floats
__device__ __forceinline__ unsigned f2key(float f) {
  union { float f; unsigned u; } v; v.f = f;
  unsigned u = v.u;
  return (u & 0x80000000u) ? ~u : (u | 0x80000000u);
}
__device__ __forceinline__ float key2f(unsigned k) {
  unsigned b = (k & 0x80000000u) ? (k ^ 0x80000000u) : ~k;
  union { unsigned u; float f; } v; v.u = b;
  return v.f;
}

__device__ __forceinline__ void gl_lds16(const void* g, void* l) {
  __builtin_amdgcn_global_load_lds(
      (const __attribute__((address_space(1))) void*)g,
      (__attribute__((address_space(3))) void*)l,
      16, 0, 0);
}

__device__ __forceinline__ float sigmoidf(float x) {
  return 1.f / (1.f + expf(-x));
}

// pack 4 floats -> 4 fp8 e4m3 bytes in one dword
__device__ __forceinline__ unsigned pk_fp8x4(float a, float b, float c, float d) {
  int w = __builtin_amdgcn_cvt_pk_fp8_f32(a, b, 0, false);   // bytes 0,1
  w = __builtin_amdgcn_cvt_pk_fp8_f32(c, d, w, true);        // bytes 2,3
  return (unsigned)w;
}

// =====================================================================
// Kernel A: PURE staging (fp8 e4m3) — unchanged from round 10.
// =====================================================================
#define QBLKS (MPAD / 16)        // 904
#define RBLKS (NPAD / 16)        // 232
__global__ __launch_bounds__(256) void stage_all_kernel(
    const float* __restrict__ q, const float* __restrict__ r,
    unsigned char* __restrict__ qb, unsigned char* __restrict__ rb,
    float* __restrict__ qinv, unsigned* __restrict__ rowmax) {
  const int blk = blockIdx.x;
  const int tid = threadIdx.x;

  // ---- staging: 16 rows per block, 16 threads per row ----
  const int g = tid >> 4;          // row group 0..15
  const int t = tid & 15;          // thread within row

  if (blk < QBLKS) {
    const int row = blk * 16 + g;
    if (t == 0) rowmax[row] = 0u;
    unsigned* dstw = (unsigned*)(qb + (long)row * D_DIM);
    if (row >= M_REAL) {
#pragma unroll
      for (int i = 0; i < 10; i++) dstw[i * 16 + t] = 0u;
      return;
    }
    const float4* src = (const float4*)(q + (long)row * D_DIM);
    float4 v[10];
    float ss = 0.f;
#pragma unroll
    for (int i = 0; i < 10; i++) {
      v[i] = src[i * 16 + t];
      ss += v[i].x * v[i].x + v[i].y * v[i].y + v[i].z * v[i].z + v[i].w * v[i].w;
    }
    ss += __shfl_xor(ss, 1); ss += __shfl_xor(ss, 2);
    ss += __shfl_xor(ss, 4); ss += __shfl_xor(ss, 8);
    float inv = 1.f / (sqrtf(ss) + 1e-6f);
    if (t == 0) qinv[row] = inv * (1.f / 16.f);  // fold r-scale
#pragma unroll
    for (int i = 0; i < 10; i++)
      dstw[i * 16 + t] = pk_fp8x4(v[i].x, v[i].y, v[i].z, v[i].w);
    return;
  }

  {
    const int row = (blk - QBLKS) * 16 + g;
    unsigned* dstw = (unsigned*)(rb + (long)row * D_DIM);
    if (row >= N_REAL) {
#pragma unroll
      for (int i = 0; i < 10; i++) dstw[i * 16 + t] = 0u;
      return;
    }
    const float4* src = (const float4*)(r + (long)row * D_DIM);
    float4 v[10];
    float ss = 0.f;
#pragma unroll
    for (int i = 0; i < 10; i++) {
      v[i] = src[i * 16 + t];
      ss += v[i].x * v[i].x + v[i].y * v[i].y + v[i].z * v[i].z + v[i].w * v[i].w;
    }
    ss += __shfl_xor(ss, 1); ss += __shfl_xor(ss, 2);
    ss += __shfl_xor(ss, 4); ss += __shfl_xor(ss, 8);
    float sc = 16.f / (sqrtf(ss) + 1e-6f);   // normalize, x16 into e4m3 normals
#pragma unroll
    for (int i = 0; i < 10; i++)
      dstw[i * 16 + t] = pk_fp8x4(v[i].x * sc, v[i].y * sc, v[i].z * sc, v[i].w * sc);
  }
}

// =====================================================================
// Kernel B: fused MX-fp8 MFMA GEMM + row-max + hidden adapter.
//   ROUND-11: counted-vmcnt pipeline (T4).  The two vmcnt(0)-draining
//   __syncthreads per K-tile are replaced by raw s_barrier + a single
//   `s_waitcnt vmcnt(8)`: after issuing the 8 gl_lds of tile kt+1, wait
//   only the OLDER 8 (tile kt) — the new 8 stay in flight across both
//   barriers.  vmcnt(0) only at the last tile.  Safety: pre-MFMA
//   barrier => every wave passed its vmcnt(8) => cur fully written;
//   post-MFMA barrier => all ds_reads of cur retired (lgkm before MFMA
//   use) before next-iter overwrite of cur.
// =====================================================================
__global__ __launch_bounds__(256) void sim_max_kernel(
    const unsigned char* __restrict__ Qb,
    const unsigned char* __restrict__ Rb,
    unsigned* __restrict__ rowmax,
    const float* __restrict__ r_img, const float* __restrict__ aw1,
    const float* __restrict__ aw2, float* __restrict__ fa) {
  __shared__ __attribute__((aligned(16))) unsigned char As[2][BM * 128];  // 2x16 KB
  __shared__ __attribute__((aligned(16))) unsigned char Bs[2][BN * 128];  // 2x16 KB

  const int xcd = blockIdx.x & 7;
  const int idx = blockIdx.x >> 3;
  const int bm = xcd + 8 * (idx % MCHUNK);
  const int bn = idx / MCHUNK;
  const int tid = threadIdx.x;

  if (bm >= MTILES) {
    // ---- adapter on spare guard blocks (xcd>=1 here by construction) ----
    const int spare = (xcd - 1) + 7 * (idx / MCHUNK);
    if (spare >= 64) return;
    const int k = spare >> 2, slice = spare & 3;

    float* Rk = (float*)&As[0][0];      // 640 floats (2.56 KB)
    float* H  = (float*)&As[0][4096];   // 160 floats
    if (tid < 160)
      ((float4*)Rk)[tid] = ((const float4*)(r_img + (size_t)k * D_DIM))[tid];
    __syncthreads();

    // H[j] = relu(sum_d Rk[d]*aw1[d][j]); 4-way d-split per j
    const int jg = tid >> 2, dp = tid & 3;
    const int dA = dp * 160;
#pragma unroll
    for (int p = 0; p < 3; p++) {
      const int j = p * 64 + jg;
      if (j < 160) {
        float a = 0.f;
#pragma unroll 8
        for (int dd = 0; dd < 160; dd++) {
          const int d = dA + dd;
          a += Rk[d] * aw1[d * 160 + j];
        }
        a += __shfl_xor(a, 1);
        a += __shfl_xor(a, 2);
        if (dp == 0) H[j] = fmaxf(a, 0.f);
      }
    }
    __syncthreads();

    // fa[k][slice*160 + t] = relu(sum_j H[j]*aw2[j][d])
    if (tid < 160) {
      const int d = slice * 160 + tid;
      float a = 0.f;
#pragma unroll 8
      for (int j = 0; j < 160; j++) a += H[j] * aw2[j * D_DIM + d];
      fa[k * D_DIM + d] = fmaxf(a, 0.f);
    }
    return;
  }

  const int wave = tid >> 6, lane = tid & 63;
  const int wr = wave >> 1, wc = wave & 1;
  const int q = lane >> 4, m0 = lane & 15;   // k-chunk (32B) / frag row

  // ---- staging geometry (pre-swizzled global source, linear LDS dest) ----
  const int sRow = tid >> 3;        // row offset within the 32-row round
  const int sp = tid & 7;           // phys chunk
  const int sSrcC = (sp ^ (sRow & 7)) << 4;  // source byte within 128B slice
  const int sLds = tid * 16;

  // ---- frag read offsets ----
  const int r7 = m0 & 7;
  const int cLo = (((q << 1) | 0) ^ r7) << 4;
  const int cHi = (((q << 1) | 1) ^ r7) << 4;

  const int aBase = bm * BM;
  const int bBase = bn * BN;

  f32x4 zero = {0.f, 0.f, 0.f, 0.f};
  f32x4 acc[4][4];
#pragma unroll
  for (int i = 0; i < 4; i++)
#pragma unroll
    for (int j = 0; j < 4; j++) acc[i][j] = zero;

  union frag_u { i32x8 v; i32x4 h[2]; };

#define STAGE_KT(KT, BUF)                                                     \
  {                                                                           \
    const int k0_ = (KT) * 128;                                               \
    _Pragma("unroll")                                                         \
    for (int rd = 0; rd < 4; rd++) {                                          \
      const int row_ = rd * 32 + sRow;                                        \
      gl_lds16(Qb + (size_t)(aBase + row_) * D_DIM + k0_ + sSrcC,             \
               &As[BUF][rd * 4096 + sLds]);                                   \
      gl_lds16(Rb + (size_t)(bBase + row_) * D_DIM + k0_ + sSrcC,             \
               &Bs[BUF][rd * 4096 + sLds]);                                   \
    }                                                                         \
  }

  // prologue: stage tile 0 (8 loads in flight; waited by kt=0's vmcnt(8))
  STAGE_KT(0, 0);

#pragma unroll
  for (int kt = 0; kt < 5; kt++) {
    const int cur = kt & 1;
    if (kt < 4) {
      // issue next tile's 8 loads, then wait only the OLDER 8 (tile kt)
      STAGE_KT(kt + 1, cur ^ 1);
      asm volatile("s_waitcnt vmcnt(8)" ::: "memory");
    } else {
      asm volatile("s_waitcnt vmcnt(0)" ::: "memory");
    }
    __builtin_amdgcn_s_barrier();   // all waves' cur-writes landed

    frag_u af[4], bf[4];
#pragma unroll
    for (int mi = 0; mi < 4; mi++) {
      const int rb_ = (wr * 64 + mi * 16 + m0) * 128;
      af[mi].h[0] = *(const i32x4*)&As[cur][rb_ + cLo];
      af[mi].h[1] = *(const i32x4*)&As[cur][rb_ + cHi];
    }
#pragma unroll
    for (int ni = 0; ni < 4; ni++) {
      const int rb_ = (wc * 64 + ni * 16 + m0) * 128;
      bf[ni].h[0] = *(const i32x4*)&Bs[cur][rb_ + cLo];
      bf[ni].h[1] = *(const i32x4*)&Bs[cur][rb_ + cHi];
    }

    __builtin_amdgcn_s_setprio(1);
#pragma unroll
    for (int mi = 0; mi < 4; mi++)
#pragma unroll
      for (int ni = 0; ni < 4; ni++)
        acc[mi][ni] = __builtin_amdgcn_mfma_scale_f32_16x16x128_f8f6f4(
            af[mi].v, bf[ni].v, acc[mi][ni],
            0 /*cbsz: A=fp8 e4m3*/, 0 /*blgp: B=fp8 e4m3*/,
            0, 0x7F7F7F7Fu /*scale A = 1.0*/,
            0, 0x7F7F7F7Fu /*scale B = 1.0*/);
    __builtin_amdgcn_s_setprio(0);

    // all waves' ds_reads of cur retired before next-iter overwrite
    if (kt < 4) __builtin_amdgcn_s_barrier();
  }
#undef STAGE_KT

  // epilogue: per-row max over this block's 128 columns, then global atomicMax
  const int colBase = bn * BN + wc * 64;
#pragma unroll
  for (int mi = 0; mi < 4; mi++) {
    float rmax[4] = {-3.0e38f, -3.0e38f, -3.0e38f, -3.0e38f};
#pragma unroll
    for (int ni = 0; ni < 4; ni++) {
      bool valid = (colBase + ni * 16 + m0) < N_REAL;
#pragma unroll
      for (int r = 0; r < 4; r++) {
        float v = valid ? acc[mi][ni][r] : -3.0e38f;
        rmax[r] = fmaxf(rmax[r], v);
      }
    }
#pragma unroll
    for (int r = 0; r < 4; r++) {
      float v = rmax[r];
      v = fmaxf(v, __shfl_xor(v, 1));
      v = fmaxf(v, __shfl_xor(v, 2));
      v = fmaxf(v, __shfl_xor(v, 4));
      v = fmaxf(v, __shfl_xor(v, 8));
      rmax[r] = v;
    }
    if (m0 == 0) {
      int row = bm * BM + wr * 64 + mi * 16 + q * 4;
#pragma unroll
      for (int r = 0; r < 4; r++)
        atomicMax(&rowmax[row + r], f2key(rmax[r]));
    }
  }
}

// =====================================================================
// Kernel C: fused tail — ONE kernel, 64 blocks (1 batch row each).
//   favg computed on the fly: mean over k of fa[k][:] (40 KB, L2).
// =====================================================================
__global__ __launch_bounds__(256) void tail_fused_kernel(
    const unsigned* __restrict__ rowmax, const float* __restrict__ qinv,
    const float* __restrict__ q_img, const float* __restrict__ fa,
    const float* __restrict__ hw1, const float* __restrict__ hb1,
    const float* __restrict__ hg2, const float* __restrict__ hbe2,
    const float* __restrict__ hw2, const float* __restrict__ hb2,
    const float* __restrict__ hg3, const float* __restrict__ hbe3,
    const float* __restrict__ hw3, const float* __restrict__ hb3,
    const float* __restrict__ rw1, const float* __restrict__ rb1,
    const float* __restrict__ rg2, const float* __restrict__ rbe2,
    const float* __restrict__ rw2, const float* __restrict__ rb2,
    const float* __restrict__ rg3, const float* __restrict__ rbe3,
    const float* __restrict__ rw3, const float* __restrict__ rb3,
    float* __restrict__ out) {
  __shared__ float A[240];    // amap row (225)
  __shared__ float R[640];    // res_img row
  __shared__ float P[256];    // GEMV1 partials
  __shared__ float Hr[128];   // ref hidden1 (post bn)
  __shared__ float Hm[128];   // map hidden1 (post bn)
  __shared__ float Q[256];    // layer2 partials (both heads)
  __shared__ float Hr2[64];   // ref hidden2
  __shared__ float Hm2[64];   // map hidden2
  __shared__ float red[16];   // [0..3] amean partials, [8]=s_ref, [9]=s_map

  const int b = blockIdx.x;
  const int tid = threadIdx.x;
  const int wave = tid >> 6, lane = tid & 63;

  // ---- amap row + amean partials; res row (favg on the fly) ----
  float am = 0.f;
  if (tid < P_DIM) {
    float mx = key2f(rowmax[b * P_DIM + tid]);
    float a = 0.5f * (1.f - mx * qinv[b * P_DIM + tid]);
    A[tid] = a;
    am = a;
  }
#pragma unroll
  for (int off = 32; off > 0; off >>= 1) am += __shfl_xor(am, off);
  if (lane == 0) red[wave] = am;
#pragma unroll
  for (int rep = 0; rep < 3; rep++) {
    int i = rep * 256 + tid;
    if (i < D_DIM) {
      float s = 0.f;
#pragma unroll
      for (int k = 0; k < 16; k++) s += fa[k * D_DIM + i];
      R[i] = q_img[b * D_DIM + i] - s * (1.f / 16.f);
    }
  }
  __syncthreads();

  const int j = tid & 127, bh = tid >> 7;

  // ---- s_ref GEMV1: 640 -> 128 (halved over bh) ----
  {
    float acc = bh ? 0.f : rb1[j];
    const int d0 = bh * 320;
#pragma unroll 8
    for (int d = 0; d < 320; d++) acc += R[d0 + d] * rw1[(d0 + d) * 128 + j];
    P[bh * 128 + j] = acc;
  }
  __syncthreads();
  if (tid < 128) Hr[tid] = fmaxf(P[tid] + P[128 + tid], 0.f) * rg2[tid] + rbe2[tid];
  __syncthreads();

  // ---- s_map GEMV1: 225 -> 128 (split 128/97 over bh) ----
  {
    float acc = bh ? 0.f : hb1[j];
    const int p0 = bh * 128;
    const int pn = bh ? (P_DIM - 128) : 128;
#pragma unroll 8
    for (int p = 0; p < pn; p++) acc += A[p0 + p] * hw1[(p0 + p) * 128 + j];
    P[bh * 128 + j] = acc;
  }
  __syncthreads();
  if (tid < 128) Hm[tid] = fmaxf(P[tid] + P[128 + tid], 0.f) * hg2[tid] + hbe2[tid];
  __syncthreads();

  // ---- layer2 both heads: 128 -> 64; g0/g1 = ref halves, g2/g3 = map ----
  {
    const int n = tid & 63, g = tid >> 6;
    const float* h = (g < 2) ? Hr : Hm;
    const float* w = (g < 2) ? rw2 : hw2;
    float acc = (g == 0) ? rb2[n] : (g == 2) ? hb2[n] : 0.f;
    const int j0 = (g & 1) * 64;
#pragma unroll 8
    for (int jj = 0; jj < 64; jj++) acc += h[j0 + jj] * w[(j0 + jj) * 64 + n];
    Q[g * 64 + n] = acc;
  }
  __syncthreads();
  if (tid < 64) Hr2[tid] = fmaxf(Q[tid] + Q[64 + tid], 0.f) * rg3[tid] + rbe3[tid];
  else if (tid < 128) {
    int n = tid - 64;
    Hm2[n] = fmaxf(Q[128 + n] + Q[192 + n], 0.f) * hg3[n] + hbe3[n];
  }
  __syncthreads();

  // ---- layer3 + sigmoid: wave 0 = ref, wave 1 = map ----
  if (wave == 0) {
    float v = Hr2[lane] * rw3[lane];
#pragma unroll
    for (int off = 32; off > 0; off >>= 1) v += __shfl_xor(v, off);
    if (lane == 0) red[8] = sigmoidf(v + rb3[0]);
  } else if (wave == 1) {
    float v = Hm2[lane] * hw3[lane];
#pragma unroll
    for (int off = 32; off > 0; off >>= 1) v += __shfl_xor(v, off);
    if (lane == 0) red[9] = sigmoidf(v + hb3[0]);
  }
  __syncthreads();

  if (tid == 0) {
    float amean = (red[0] + red[1] + red[2] + red[3]) * (1.f / 225.f);
    out[b] = 0.5f * (red[8] + red[9]) + amean;
  }
}

// ---------------- launch ----------------
extern "C" void kernel_launch(void* const* d_in, const int* in_sizes, int n_in,
                              void* d_out, int out_size, void* d_ws, size_t ws_size,
                              hipStream_t stream) {
  const float* q_patch = (const float*)d_in[0];
  const float* r_patch = (const float*)d_in[1];
  const float* q_img   = (const float*)d_in[2];
  const float* r_img   = (const float*)d_in[3];
  const float* adpt_w1 = (const float*)d_in[4];
  const float* adpt_w2 = (const float*)d_in[5];
  const float* dh_w1 = (const float*)d_in[6];
  const float* dh_b1 = (const float*)d_in[7];
  const float* dh_g2 = (const float*)d_in[8];
  const float* dh_be2 = (const float*)d_in[9];
  const float* dh_w2 = (const float*)d_in[10];
  const float* dh_b2 = (const float*)d_in[11];
  const float* dh_g3 = (const float*)d_in[12];
  const float* dh_be3 = (const float*)d_in[13];
  const float* dh_w3 = (const float*)d_in[14];
  const float* dh_b3 = (const float*)d_in[15];
  const float* dr_w1 = (const float*)d_in[16];
  const float* dr_b1 = (const float*)d_in[17];
  const float* dr_g2 = (const float*)d_in[18];
  const float* dr_be2 = (const float*)d_in[19];
  const float* dr_w2 = (const float*)d_in[20];
  const float* dr_b2 = (const float*)d_in[21];
  const float* dr_g3 = (const float*)d_in[22];
  const float* dr_be3 = (const float*)d_in[23];
  const float* dr_w3 = (const float*)d_in[24];
  const float* dr_b3 = (const float*)d_in[25];

  // ws layout (bytes) — fp8 staging buffers
  const size_t QB_BYTES = (size_t)MPAD * D_DIM;   // 9,256,960
  const size_t RB_BYTES = (size_t)NPAD * D_DIM;   // 2,375,680
  char* ws = (char*)d_ws;
  unsigned char* qb = (unsigned char*)(ws);
  unsigned char* rb = (unsigned char*)(ws + QB_BYTES);
  float* qinv        = (float*)(ws + QB_BYTES + RB_BYTES);
  unsigned* rowmax   = (unsigned*)(ws + QB_BYTES + RB_BYTES + (size_t)M_REAL * 4);
  float* fa          = (float*)(ws + QB_BYTES + RB_BYTES + (size_t)M_REAL * 4 + (size_t)MPAD * 4);

  stage_all_kernel<<<QBLKS + RBLKS, 256, 0, stream>>>(
      q_patch, r_patch, qb, rb, qinv, rowmax);
  sim_max_kernel<<<8 * MCHUNK * NTILES, 256, 0, stream>>>(
      qb, rb, rowmax, r_img, adpt_w1, adpt_w2, fa);
  tail_fused_kernel<<<B_DIM, 256, 0, stream>>>(
      rowmax, qinv, q_img, fa,
      dh_w1, dh_b1, dh_g2, dh_be2, dh_w2, dh_b2, dh_g3, dh_be3, dh_w3, dh_b3,
      dr_w1, dr_b1, dr_g2, dr_be2, dr_w2, dr_b2, dr_g3, dr_be3, dr_w3, dr_b3,
      (float*)d_out);
}

// Round 12
// 208.647 us; speedup vs baseline: 1.0254x; 1.0254x over previous
//
#include <hip/hip_runtime.h>
#include <stdint.h>

// ---------------- problem dims ----------------
#define B_DIM 64
#define P_DIM 225
#define K_DIM 16
#define D_DIM 640
#define M_REAL (B_DIM * P_DIM)   // 14400 query rows
#define N_REAL (K_DIM * P_DIM)   // 3600 reference rows

// ---------------- GEMM tiling ----------------
#define BM 128
#define BN 128
#define MTILES 113               // ceil(14400/128) -> Mpad 14464
#define NTILES 29                // ceil(3600/128)  -> Npad 3712
#define MPAD (MTILES * BM)
#define NPAD (NTILES * BN)
#define MCHUNK 15                // ceil(MTILES/8) per-XCD bm groups

typedef float f32x4 __attribute__((ext_vector_type(4)));
typedef int   i32x4 __attribute__((ext_vector_type(4)));
typedef int   i32x8 __attribute__((ext_vector_type(8)));

// ---------------- helpers ----------------
// monotone float -> uint key (order-preserving), for atomicMax on floats
__device__ __forceinline__ unsigned f2key(float f) {
  union { float f; unsigned u; } v; v.f = f;
  unsigned u = v.u;
  return (u & 0x80000000u) ? ~u : (u | 0x80000000u);
}
__device__ __forceinline__ float key2f(unsigned k) {
  unsigned b = (k & 0x80000000u) ? (k ^ 0x80000000u) : ~k;
  union { unsigned u; float f; } v; v.u = b;
  return v.f;
}

__device__ __forceinline__ void gl_lds16(const void* g, void* l) {
  __builtin_amdgcn_global_load_lds(
      (const __attribute__((address_space(1))) void*)g,
      (__attribute__((address_space(3))) void*)l,
      16, 0, 0);
}

__device__ __forceinline__ float sigmoidf(float x) {
  return 1.f / (1.f + expf(-x));
}

// pack 4 floats -> 4 fp8 e4m3 bytes in one dword
__device__ __forceinline__ unsigned pk_fp8x4(float a, float b, float c, float d) {
  int w = __builtin_amdgcn_cvt_pk_fp8_f32(a, b, 0, false);   // bytes 0,1
  w = __builtin_amdgcn_cvt_pk_fp8_f32(c, d, w, true);        // bytes 2,3
  return (unsigned)w;
}

// =====================================================================
// Kernel A: PURE staging (fp8 e4m3) — unchanged from round 10.
// =====================================================================
#define QBLKS (MPAD / 16)        // 904
#define RBLKS (NPAD / 16)        // 232
__global__ __launch_bounds__(256) void stage_all_kernel(
    const float* __restrict__ q, const float* __restrict__ r,
    unsigned char* __restrict__ qb, unsigned char* __restrict__ rb,
    float* __restrict__ qinv, unsigned* __restrict__ rowmax) {
  const int blk = blockIdx.x;
  const int tid = threadIdx.x;

  // ---- staging: 16 rows per block, 16 threads per row ----
  const int g = tid >> 4;          // row group 0..15
  const int t = tid & 15;          // thread within row

  if (blk < QBLKS) {
    const int row = blk * 16 + g;
    if (t == 0) rowmax[row] = 0u;
    unsigned* dstw = (unsigned*)(qb + (long)row * D_DIM);
    if (row >= M_REAL) {
#pragma unroll
      for (int i = 0; i < 10; i++) dstw[i * 16 + t] = 0u;
      return;
    }
    const float4* src = (const float4*)(q + (long)row * D_DIM);
    float4 v[10];
    float ss = 0.f;
#pragma unroll
    for (int i = 0; i < 10; i++) {
      v[i] = src[i * 16 + t];
      ss += v[i].x * v[i].x + v[i].y * v[i].y + v[i].z * v[i].z + v[i].w * v[i].w;
    }
    ss += __shfl_xor(ss, 1); ss += __shfl_xor(ss, 2);
    ss += __shfl_xor(ss, 4); ss += __shfl_xor(ss, 8);
    float inv = 1.f / (sqrtf(ss) + 1e-6f);
    if (t == 0) qinv[row] = inv * (1.f / 16.f);  // fold r-scale
#pragma unroll
    for (int i = 0; i < 10; i++)
      dstw[i * 16 + t] = pk_fp8x4(v[i].x, v[i].y, v[i].z, v[i].w);
    return;
  }

  {
    const int row = (blk - QBLKS) * 16 + g;
    unsigned* dstw = (unsigned*)(rb + (long)row * D_DIM);
    if (row >= N_REAL) {
#pragma unroll
      for (int i = 0; i < 10; i++) dstw[i * 16 + t] = 0u;
      return;
    }
    const float4* src = (const float4*)(r + (long)row * D_DIM);
    float4 v[10];
    float ss = 0.f;
#pragma unroll
    for (int i = 0; i < 10; i++) {
      v[i] = src[i * 16 + t];
      ss += v[i].x * v[i].x + v[i].y * v[i].y + v[i].z * v[i].z + v[i].w * v[i].w;
    }
    ss += __shfl_xor(ss, 1); ss += __shfl_xor(ss, 2);
    ss += __shfl_xor(ss, 4); ss += __shfl_xor(ss, 8);
    float sc = 16.f / (sqrtf(ss) + 1e-6f);   // normalize, x16 into e4m3 normals
#pragma unroll
    for (int i = 0; i < 10; i++)
      dstw[i * 16 + t] = pk_fp8x4(v[i].x * sc, v[i].y * sc, v[i].z * sc, v[i].w * sc);
  }
}

// =====================================================================
// Kernel B: fused MX-fp8 MFMA GEMM + row-max + hidden adapter.
//   ROUND-12: SINGLE-buffer LDS (32 KB vs 64 KB) -> 5 blocks/CU
//   (was 2; VGPR=88 allows 5 waves/SIMD, LDS was the binding limit).
//   Round-11's counted-vmcnt was null: at 2 blocks/CU the drains were
//   already hidden (m114 regime); the stall-glue (~54% of cycles, no
//   pipe >35%) compresses via TLP, not waitcnt plumbing.
//   Per-iter order keeps prefetch overlap WITHOUT a second buffer:
//     ds_read frags -> lgkmcnt(0) -> barrier      (all reads landed)
//     gl_lds(kt+1 into SAME buffer)               (issue-early)
//     MFMA cluster                                 (covers load flight)
//     vmcnt(0) -> barrier                          (tile kt+1 resident)
// =====================================================================
__global__ __launch_bounds__(256) void sim_max_kernel(
    const unsigned char* __restrict__ Qb,
    const unsigned char* __restrict__ Rb,
    unsigned* __restrict__ rowmax,
    const float* __restrict__ r_img, const float* __restrict__ aw1,
    const float* __restrict__ aw2, float* __restrict__ fa) {
  __shared__ __attribute__((aligned(16))) unsigned char As[BM * 128];  // 16 KB
  __shared__ __attribute__((aligned(16))) unsigned char Bs[BN * 128];  // 16 KB

  const int xcd = blockIdx.x & 7;
  const int idx = blockIdx.x >> 3;
  const int bm = xcd + 8 * (idx % MCHUNK);
  const int bn = idx / MCHUNK;
  const int tid = threadIdx.x;

  if (bm >= MTILES) {
    // ---- adapter on spare guard blocks (xcd>=1 here by construction) ----
    const int spare = (xcd - 1) + 7 * (idx / MCHUNK);
    if (spare >= 64) return;
    const int k = spare >> 2, slice = spare & 3;

    float* Rk = (float*)&As[0];      // 640 floats (2.56 KB)
    float* H  = (float*)&As[4096];   // 160 floats
    if (tid < 160)
      ((float4*)Rk)[tid] = ((const float4*)(r_img + (size_t)k * D_DIM))[tid];
    __syncthreads();

    // H[j] = relu(sum_d Rk[d]*aw1[d][j]); 4-way d-split per j
    const int jg = tid >> 2, dp = tid & 3;
    const int dA = dp * 160;
#pragma unroll
    for (int p = 0; p < 3; p++) {
      const int j = p * 64 + jg;
      if (j < 160) {
        float a = 0.f;
#pragma unroll 8
        for (int dd = 0; dd < 160; dd++) {
          const int d = dA + dd;
          a += Rk[d] * aw1[d * 160 + j];
        }
        a += __shfl_xor(a, 1);
        a += __shfl_xor(a, 2);
        if (dp == 0) H[j] = fmaxf(a, 0.f);
      }
    }
    __syncthreads();

    // fa[k][slice*160 + t] = relu(sum_j H[j]*aw2[j][d])
    if (tid < 160) {
      const int d = slice * 160 + tid;
      float a = 0.f;
#pragma unroll 8
      for (int j = 0; j < 160; j++) a += H[j] * aw2[j * D_DIM + d];
      fa[k * D_DIM + d] = fmaxf(a, 0.f);
    }
    return;
  }

  const int wave = tid >> 6, lane = tid & 63;
  const int wr = wave >> 1, wc = wave & 1;
  const int q = lane >> 4, m0 = lane & 15;   // k-chunk (32B) / frag row

  // ---- staging geometry (pre-swizzled global source, linear LDS dest) ----
  const int sRow = tid >> 3;        // row offset within the 32-row round
  const int sp = tid & 7;           // phys chunk
  const int sSrcC = (sp ^ (sRow & 7)) << 4;  // source byte within 128B slice
  const int sLds = tid * 16;

  // ---- frag read offsets ----
  const int r7 = m0 & 7;
  const int cLo = (((q << 1) | 0) ^ r7) << 4;
  const int cHi = (((q << 1) | 1) ^ r7) << 4;

  const int aBase = bm * BM;
  const int bBase = bn * BN;

  f32x4 zero = {0.f, 0.f, 0.f, 0.f};
  f32x4 acc[4][4];
#pragma unroll
  for (int i = 0; i < 4; i++)
#pragma unroll
    for (int j = 0; j < 4; j++) acc[i][j] = zero;

  union frag_u { i32x8 v; i32x4 h[2]; };

#define STAGE_KT(KT)                                                          \
  {                                                                           \
    const int k0_ = (KT) * 128;                                               \
    _Pragma("unroll")                                                         \
    for (int rd = 0; rd < 4; rd++) {                                          \
      const int row_ = rd * 32 + sRow;                                        \
      gl_lds16(Qb + (size_t)(aBase + row_) * D_DIM + k0_ + sSrcC,             \
               &As[rd * 4096 + sLds]);                                        \
      gl_lds16(Rb + (size_t)(bBase + row_) * D_DIM + k0_ + sSrcC,             \
               &Bs[rd * 4096 + sLds]);                                        \
    }                                                                         \
  }

  // prologue: stage tile 0, drain, gate
  STAGE_KT(0);
  asm volatile("s_waitcnt vmcnt(0)" ::: "memory");
  __builtin_amdgcn_s_barrier();

#pragma unroll
  for (int kt = 0; kt < 5; kt++) {
    // ---- read this tile's fragments into registers ----
    frag_u af[4], bf[4];
#pragma unroll
    for (int mi = 0; mi < 4; mi++) {
      const int rb_ = (wr * 64 + mi * 16 + m0) * 128;
      af[mi].h[0] = *(const i32x4*)&As[rb_ + cLo];
      af[mi].h[1] = *(const i32x4*)&As[rb_ + cHi];
    }
#pragma unroll
    for (int ni = 0; ni < 4; ni++) {
      const int rb_ = (wc * 64 + ni * 16 + m0) * 128;
      bf[ni].h[0] = *(const i32x4*)&Bs[rb_ + cLo];
      bf[ni].h[1] = *(const i32x4*)&Bs[rb_ + cHi];
    }
    // all of this wave's reads LANDED, then all waves passed -> safe to
    // overwrite the (single) buffer with the next tile
    asm volatile("s_waitcnt lgkmcnt(0)" ::: "memory");
    __builtin_amdgcn_s_barrier();
    if (kt < 4) STAGE_KT(kt + 1);

    __builtin_amdgcn_s_setprio(1);
#pragma unroll
    for (int mi = 0; mi < 4; mi++)
#pragma unroll
      for (int ni = 0; ni < 4; ni++)
        acc[mi][ni] = __builtin_amdgcn_mfma_scale_f32_16x16x128_f8f6f4(
            af[mi].v, bf[ni].v, acc[mi][ni],
            0 /*cbsz: A=fp8 e4m3*/, 0 /*blgp: B=fp8 e4m3*/,
            0, 0x7F7F7F7Fu /*scale A = 1.0*/,
            0, 0x7F7F7F7Fu /*scale B = 1.0*/);
    __builtin_amdgcn_s_setprio(0);

    if (kt < 4) {
      // next tile fully resident before any wave's next-iter ds_read
      asm volatile("s_waitcnt vmcnt(0)" ::: "memory");
      __builtin_amdgcn_s_barrier();
    }
  }
#undef STAGE_KT

  // epilogue: per-row max over this block's 128 columns, then global atomicMax
  const int colBase = bn * BN + wc * 64;
#pragma unroll
  for (int mi = 0; mi < 4; mi++) {
    float rmax[4] = {-3.0e38f, -3.0e38f, -3.0e38f, -3.0e38f};
#pragma unroll
    for (int ni = 0; ni < 4; ni++) {
      bool valid = (colBase + ni * 16 + m0) < N_REAL;
#pragma unroll
      for (int r = 0; r < 4; r++) {
        float v = valid ? acc[mi][ni][r] : -3.0e38f;
        rmax[r] = fmaxf(rmax[r], v);
      }
    }
#pragma unroll
    for (int r = 0; r < 4; r++) {
      float v = rmax[r];
      v = fmaxf(v, __shfl_xor(v, 1));
      v = fmaxf(v, __shfl_xor(v, 2));
      v = fmaxf(v, __shfl_xor(v, 4));
      v = fmaxf(v, __shfl_xor(v, 8));
      rmax[r] = v;
    }
    if (m0 == 0) {
      int row = bm * BM + wr * 64 + mi * 16 + q * 4;
#pragma unroll
      for (int r = 0; r < 4; r++)
        atomicMax(&rowmax[row + r], f2key(rmax[r]));
    }
  }
}

// =====================================================================
// Kernel C: fused tail — ONE kernel, 64 blocks (1 batch row each).
//   favg computed on the fly: mean over k of fa[k][:] (40 KB, L2).
// =====================================================================
__global__ __launch_bounds__(256) void tail_fused_kernel(
    const unsigned* __restrict__ rowmax, const float* __restrict__ qinv,
    const float* __restrict__ q_img, const float* __restrict__ fa,
    const float* __restrict__ hw1, const float* __restrict__ hb1,
    const float* __restrict__ hg2, const float* __restrict__ hbe2,
    const float* __restrict__ hw2, const float* __restrict__ hb2,
    const float* __restrict__ hg3, const float* __restrict__ hbe3,
    const float* __restrict__ hw3, const float* __restrict__ hb3,
    const float* __restrict__ rw1, const float* __restrict__ rb1,
    const float* __restrict__ rg2, const float* __restrict__ rbe2,
    const float* __restrict__ rw2, const float* __restrict__ rb2,
    const float* __restrict__ rg3, const float* __restrict__ rbe3,
    const float* __restrict__ rw3, const float* __restrict__ rb3,
    float* __restrict__ out) {
  __shared__ float A[240];    // amap row (225)
  __shared__ float R[640];    // res_img row
  __shared__ float P[256];    // GEMV1 partials
  __shared__ float Hr[128];   // ref hidden1 (post bn)
  __shared__ float Hm[128];   // map hidden1 (post bn)
  __shared__ float Q[256];    // layer2 partials (both heads)
  __shared__ float Hr2[64];   // ref hidden2
  __shared__ float Hm2[64];   // map hidden2
  __shared__ float red[16];   // [0..3] amean partials, [8]=s_ref, [9]=s_map

  const int b = blockIdx.x;
  const int tid = threadIdx.x;
  const int wave = tid >> 6, lane = tid & 63;

  // ---- amap row + amean partials; res row (favg on the fly) ----
  float am = 0.f;
  if (tid < P_DIM) {
    float mx = key2f(rowmax[b * P_DIM + tid]);
    float a = 0.5f * (1.f - mx * qinv[b * P_DIM + tid]);
    A[tid] = a;
    am = a;
  }
#pragma unroll
  for (int off = 32; off > 0; off >>= 1) am += __shfl_xor(am, off);
  if (lane == 0) red[wave] = am;
#pragma unroll
  for (int rep = 0; rep < 3; rep++) {
    int i = rep * 256 + tid;
    if (i < D_DIM) {
      float s = 0.f;
#pragma unroll
      for (int k = 0; k < 16; k++) s += fa[k * D_DIM + i];
      R[i] = q_img[b * D_DIM + i] - s * (1.f / 16.f);
    }
  }
  __syncthreads();

  const int j = tid & 127, bh = tid >> 7;

  // ---- s_ref GEMV1: 640 -> 128 (halved over bh) ----
  {
    float acc = bh ? 0.f : rb1[j];
    const int d0 = bh * 320;
#pragma unroll 8
    for (int d = 0; d < 320; d++) acc += R[d0 + d] * rw1[(d0 + d) * 128 + j];
    P[bh * 128 + j] = acc;
  }
  __syncthreads();
  if (tid < 128) Hr[tid] = fmaxf(P[tid] + P[128 + tid], 0.f) * rg2[tid] + rbe2[tid];
  __syncthreads();

  // ---- s_map GEMV1: 225 -> 128 (split 128/97 over bh) ----
  {
    float acc = bh ? 0.f : hb1[j];
    const int p0 = bh * 128;
    const int pn = bh ? (P_DIM - 128) : 128;
#pragma unroll 8
    for (int p = 0; p < pn; p++) acc += A[p0 + p] * hw1[(p0 + p) * 128 + j];
    P[bh * 128 + j] = acc;
  }
  __syncthreads();
  if (tid < 128) Hm[tid] = fmaxf(P[tid] + P[128 + tid], 0.f) * hg2[tid] + hbe2[tid];
  __syncthreads();

  // ---- layer2 both heads: 128 -> 64; g0/g1 = ref halves, g2/g3 = map ----
  {
    const int n = tid & 63, g = tid >> 6;
    const float* h = (g < 2) ? Hr : Hm;
    const float* w = (g < 2) ? rw2 : hw2;
    float acc = (g == 0) ? rb2[n] : (g == 2) ? hb2[n] : 0.f;
    const int j0 = (g & 1) * 64;
#pragma unroll 8
    for (int jj = 0; jj < 64; jj++) acc += h[j0 + jj] * w[(j0 + jj) * 64 + n];
    Q[g * 64 + n] = acc;
  }
  __syncthreads();
  if (tid < 64) Hr2[tid] = fmaxf(Q[tid] + Q[64 + tid], 0.f) * rg3[tid] + rbe3[tid];
  else if (tid < 128) {
    int n = tid - 64;
    Hm2[n] = fmaxf(Q[128 + n] + Q[192 + n], 0.f) * hg3[n] + hbe3[n];
  }
  __syncthreads();

  // ---- layer3 + sigmoid: wave 0 = ref, wave 1 = map ----
  if (wave == 0) {
    float v = Hr2[lane] * rw3[lane];
#pragma unroll
    for (int off = 32; off > 0; off >>= 1) v += __shfl_xor(v, off);
    if (lane == 0) red[8] = sigmoidf(v + rb3[0]);
  } else if (wave == 1) {
    float v = Hm2[lane] * hw3[lane];
#pragma unroll
    for (int off = 32; off > 0; off >>= 1) v += __shfl_xor(v, off);
    if (lane == 0) red[9] = sigmoidf(v + hb3[0]);
  }
  __syncthreads();

  if (tid == 0) {
    float amean = (red[0] + red[1] + red[2] + red[3]) * (1.f / 225.f);
    out[b] = 0.5f * (red[8] + red[9]) + amean;
  }
}

// ---------------- launch ----------------
extern "C" void kernel_launch(void* const* d_in, const int* in_sizes, int n_in,
                              void* d_out, int out_size, void* d_ws, size_t ws_size,
                              hipStream_t stream) {
  const float* q_patch = (const float*)d_in[0];
  const float* r_patch = (const float*)d_in[1];
  const float* q_img   = (const float*)d_in[2];
  const float* r_img   = (const float*)d_in[3];
  const float* adpt_w1 = (const float*)d_in[4];
  const float* adpt_w2 = (const float*)d_in[5];
  const float* dh_w1 = (const float*)d_in[6];
  const float* dh_b1 = (const float*)d_in[7];
  const float* dh_g2 = (const float*)d_in[8];
  const float* dh_be2 = (const float*)d_in[9];
  const float* dh_w2 = (const float*)d_in[10];
  const float* dh_b2 = (const float*)d_in[11];
  const float* dh_g3 = (const float*)d_in[12];
  const float* dh_be3 = (const float*)d_in[13];
  const float* dh_w3 = (const float*)d_in[14];
  const float* dh_b3 = (const float*)d_in[15];
  const float* dr_w1 = (const float*)d_in[16];
  const float* dr_b1 = (const float*)d_in[17];
  const float* dr_g2 = (const float*)d_in[18];
  const float* dr_be2 = (const float*)d_in[19];
  const float* dr_w2 = (const float*)d_in[20];
  const float* dr_b2 = (const float*)d_in[21];
  const float* dr_g3 = (const float*)d_in[22];
  const float* dr_be3 = (const float*)d_in[23];
  const float* dr_w3 = (const float*)d_in[24];
  const float* dr_b3 = (const float*)d_in[25];

  // ws layout (bytes) — fp8 staging buffers
  const size_t QB_BYTES = (size_t)MPAD * D_DIM;   // 9,256,960
  const size_t RB_BYTES = (size_t)NPAD * D_DIM;   // 2,375,680
  char* ws = (char*)d_ws;
  unsigned char* qb = (unsigned char*)(ws);
  unsigned char* rb = (unsigned char*)(ws + QB_BYTES);
  float* qinv        = (float*)(ws + QB_BYTES + RB_BYTES);
  unsigned* rowmax   = (unsigned*)(ws + QB_BYTES + RB_BYTES + (size_t)M_REAL * 4);
  float* fa          = (float*)(ws + QB_BYTES + RB_BYTES + (size_t)M_REAL * 4 + (size_t)MPAD * 4);

  stage_all_kernel<<<QBLKS + RBLKS, 256, 0, stream>>>(
      q_patch, r_patch, qb, rb, qinv, rowmax);
  sim_max_kernel<<<8 * MCHUNK * NTILES, 256, 0, stream>>>(
      qb, rb, rowmax, r_img, adpt_w1, adpt_w2, fa);
  tail_fused_kernel<<<B_DIM, 256, 0, stream>>>(
      rowmax, qinv, q_img, fa,
      dh_w1, dh_b1, dh_g2, dh_be2, dh_w2, dh_b2, dh_g3, dh_be3, dh_w3, dh_b3,
      dr_w1, dr_b1, dr_g2, dr_be2, dr_w2, dr_b2, dr_g3, dr_be3, dr_w3, dr_b3,
      (float*)d_out);
}

// Round 13
// 208.160 us; speedup vs baseline: 1.0278x; 1.0023x over previous
//
#include <hip/hip_runtime.h>
#include <stdint.h>

// ---------------- problem dims ----------------
#define B_DIM 64
#define P_DIM 225
#define K_DIM 16
#define D_DIM 640
#define M_REAL (B_DIM * P_DIM)   // 14400 query rows
#define N_REAL (K_DIM * P_DIM)   // 3600 reference rows

// ---------------- GEMM tiling ----------------
#define BM 128
#define BN 128
#define MTILES 113               // ceil(14400/128) -> Mpad 14464
#define NTILES 29                // ceil(3600/128)  -> Npad 3712
#define MPAD (MTILES * BM)
#define NPAD (NTILES * BN)
#define MCHUNK 15                // ceil(MTILES/8) per-XCD bm groups

typedef float f32x4 __attribute__((ext_vector_type(4)));
typedef int   i32x4 __attribute__((ext_vector_type(4)));
typedef int   i32x8 __attribute__((ext_vector_type(8)));

// ---------------- helpers ----------------
// monotone float -> uint key (order-preserving), for atomicMax on floats
__device__ __forceinline__ unsigned f2key(float f) {
  union { float f; unsigned u; } v; v.f = f;
  unsigned u = v.u;
  return (u & 0x80000000u) ? ~u : (u | 0x80000000u);
}
__device__ __forceinline__ float key2f(unsigned k) {
  unsigned b = (k & 0x80000000u) ? (k ^ 0x80000000u) : ~k;
  union { unsigned u; float f; } v; v.u = b;
  return v.f;
}

__device__ __forceinline__ void gl_lds16(const void* g, void* l) {
  __builtin_amdgcn_global_load_lds(
      (const __attribute__((address_space(1))) void*)g,
      (__attribute__((address_space(3))) void*)l,
      16, 0, 0);
}

__device__ __forceinline__ float sigmoidf(float x) {
  return 1.f / (1.f + expf(-x));
}

// pack 4 floats -> 4 fp8 e4m3 bytes in one dword
__device__ __forceinline__ unsigned pk_fp8x4(float a, float b, float c, float d) {
  int w = __builtin_amdgcn_cvt_pk_fp8_f32(a, b, 0, false);   // bytes 0,1
  w = __builtin_amdgcn_cvt_pk_fp8_f32(c, d, w, true);        // bytes 2,3
  return (unsigned)w;
}

// =====================================================================
// Kernel A: PURE staging (fp8 e4m3) — unchanged from round 10.
// =====================================================================
#define QBLKS (MPAD / 16)        // 904
#define RBLKS (NPAD / 16)        // 232
__global__ __launch_bounds__(256) void stage_all_kernel(
    const float* __restrict__ q, const float* __restrict__ r,
    unsigned char* __restrict__ qb, unsigned char* __restrict__ rb,
    float* __restrict__ qinv, unsigned* __restrict__ rowmax) {
  const int blk = blockIdx.x;
  const int tid = threadIdx.x;

  // ---- staging: 16 rows per block, 16 threads per row ----
  const int g = tid >> 4;          // row group 0..15
  const int t = tid & 15;          // thread within row

  if (blk < QBLKS) {
    const int row = blk * 16 + g;
    if (t == 0) rowmax[row] = 0u;
    unsigned* dstw = (unsigned*)(qb + (long)row * D_DIM);
    if (row >= M_REAL) {
#pragma unroll
      for (int i = 0; i < 10; i++) dstw[i * 16 + t] = 0u;
      return;
    }
    const float4* src = (const float4*)(q + (long)row * D_DIM);
    float4 v[10];
    float ss = 0.f;
#pragma unroll
    for (int i = 0; i < 10; i++) {
      v[i] = src[i * 16 + t];
      ss += v[i].x * v[i].x + v[i].y * v[i].y + v[i].z * v[i].z + v[i].w * v[i].w;
    }
    ss += __shfl_xor(ss, 1); ss += __shfl_xor(ss, 2);
    ss += __shfl_xor(ss, 4); ss += __shfl_xor(ss, 8);
    float inv = 1.f / (sqrtf(ss) + 1e-6f);
    if (t == 0) qinv[row] = inv * (1.f / 16.f);  // fold r-scale
#pragma unroll
    for (int i = 0; i < 10; i++)
      dstw[i * 16 + t] = pk_fp8x4(v[i].x, v[i].y, v[i].z, v[i].w);
    return;
  }

  {
    const int row = (blk - QBLKS) * 16 + g;
    unsigned* dstw = (unsigned*)(rb + (long)row * D_DIM);
    if (row >= N_REAL) {
#pragma unroll
      for (int i = 0; i < 10; i++) dstw[i * 16 + t] = 0u;
      return;
    }
    const float4* src = (const float4*)(r + (long)row * D_DIM);
    float4 v[10];
    float ss = 0.f;
#pragma unroll
    for (int i = 0; i < 10; i++) {
      v[i] = src[i * 16 + t];
      ss += v[i].x * v[i].x + v[i].y * v[i].y + v[i].z * v[i].z + v[i].w * v[i].w;
    }
    ss += __shfl_xor(ss, 1); ss += __shfl_xor(ss, 2);
    ss += __shfl_xor(ss, 4); ss += __shfl_xor(ss, 8);
    float sc = 16.f / (sqrtf(ss) + 1e-6f);   // normalize, x16 into e4m3 normals
#pragma unroll
    for (int i = 0; i < 10; i++)
      dstw[i * 16 + t] = pk_fp8x4(v[i].x * sc, v[i].y * sc, v[i].z * sc, v[i].w * sc);
  }
}

// =====================================================================
// Kernel B: fused MX-fp8 MFMA GEMM + row-max + hidden adapter.
//   ROUND-13: register-bucket fix.  Round-12 showed Occupancy stuck at
//   18.6% = 2 waves/SIMD regardless of LDS: unified regs were 88 VGPR +
//   64 AGPR = 152 -> the 256-reg bucket (m69: waves/SIMD steps at
//   64/128/256).  Now: 8 waves x acc[2][4] (32 AGPR, 32x64 out/wave)
//   covers the same 128x128 tile with ~75 VGPR + 32 AGPR ~ 107 <= 128
//   -> 4 waves/SIMD (2 blocks/CU, 16 waves/CU).  __launch_bounds__
//   (512,4) pins the 128-reg cap (20+ regs of margin, unlike round 3).
//   Single-buffer barrier discipline unchanged from round 12.
// =====================================================================
__global__ __launch_bounds__(512, 4) void sim_max_kernel(
    const unsigned char* __restrict__ Qb,
    const unsigned char* __restrict__ Rb,
    unsigned* __restrict__ rowmax,
    const float* __restrict__ r_img, const float* __restrict__ aw1,
    const float* __restrict__ aw2, float* __restrict__ fa) {
  __shared__ __attribute__((aligned(16))) unsigned char As[BM * 128];  // 16 KB
  __shared__ __attribute__((aligned(16))) unsigned char Bs[BN * 128];  // 16 KB

  const int xcd = blockIdx.x & 7;
  const int idx = blockIdx.x >> 3;
  const int bm = xcd + 8 * (idx % MCHUNK);
  const int bn = idx / MCHUNK;
  const int tid = threadIdx.x;

  if (bm >= MTILES) {
    // ---- adapter on spare guard blocks (xcd>=1 here by construction) ----
    const int spare = (xcd - 1) + 7 * (idx / MCHUNK);
    if (spare >= 64) return;
    const int k = spare >> 2, slice = spare & 3;

    float* Rk = (float*)&As[0];      // 640 floats (2.56 KB)
    float* H  = (float*)&As[4096];   // 160 floats
    if (tid < 160)
      ((float4*)Rk)[tid] = ((const float4*)(r_img + (size_t)k * D_DIM))[tid];
    __syncthreads();

    // H[j] = relu(sum_d Rk[d]*aw1[d][j]); 4-way d-split per j (512 thr)
    const int jg = tid >> 2, dp = tid & 3;   // jg 0..127
    const int dA = dp * 160;
#pragma unroll
    for (int p = 0; p < 2; p++) {
      const int j = p * 128 + jg;
      if (j < 160) {
        float a = 0.f;
#pragma unroll 8
        for (int dd = 0; dd < 160; dd++) {
          const int d = dA + dd;
          a += Rk[d] * aw1[d * 160 + j];
        }
        a += __shfl_xor(a, 1);
        a += __shfl_xor(a, 2);
        if (dp == 0) H[j] = fmaxf(a, 0.f);
      }
    }
    __syncthreads();

    // fa[k][slice*160 + t] = relu(sum_j H[j]*aw2[j][d])
    if (tid < 160) {
      const int d = slice * 160 + tid;
      float a = 0.f;
#pragma unroll 8
      for (int j = 0; j < 160; j++) a += H[j] * aw2[j * D_DIM + d];
      fa[k * D_DIM + d] = fmaxf(a, 0.f);
    }
    return;
  }

  const int wave = tid >> 6, lane = tid & 63;  // 8 waves
  const int wr = wave >> 1, wc = wave & 1;     // 4 x 2 wave grid
  const int q = lane >> 4, m0 = lane & 15;     // k-chunk (32B) / frag row

  // ---- staging geometry: 512 threads cover 64 rows x 8 chunks / round ----
  const int sRow = tid >> 3;        // 0..63
  const int sp = tid & 7;           // phys chunk
  const int sSrcC = (sp ^ (sRow & 7)) << 4;  // pre-swizzled source byte
  const int sLds = tid * 16;        // linear LDS dest within round (8 KB)

  // ---- frag read offsets ----
  const int r7 = m0 & 7;
  const int cLo = (((q << 1) | 0) ^ r7) << 4;
  const int cHi = (((q << 1) | 1) ^ r7) << 4;

  const int aBase = bm * BM;
  const int bBase = bn * BN;

  f32x4 zero = {0.f, 0.f, 0.f, 0.f};
  f32x4 acc[2][4];
#pragma unroll
  for (int i = 0; i < 2; i++)
#pragma unroll
    for (int j = 0; j < 4; j++) acc[i][j] = zero;

  union frag_u { i32x8 v; i32x4 h[2]; };

#define STAGE_KT(KT)                                                          \
  {                                                                           \
    const int k0_ = (KT) * 128;                                               \
    _Pragma("unroll")                                                         \
    for (int rd = 0; rd < 2; rd++) {                                          \
      const int row_ = rd * 64 + sRow;                                        \
      gl_lds16(Qb + (size_t)(aBase + row_) * D_DIM + k0_ + sSrcC,             \
               &As[rd * 8192 + sLds]);                                        \
      gl_lds16(Rb + (size_t)(bBase + row_) * D_DIM + k0_ + sSrcC,             \
               &Bs[rd * 8192 + sLds]);                                        \
    }                                                                         \
  }

  // prologue: stage tile 0, drain, gate
  STAGE_KT(0);
  asm volatile("s_waitcnt vmcnt(0)" ::: "memory");
  __builtin_amdgcn_s_barrier();

#pragma unroll
  for (int kt = 0; kt < 5; kt++) {
    // ---- read this tile's fragments into registers ----
    frag_u af[2], bf[4];
#pragma unroll
    for (int mi = 0; mi < 2; mi++) {
      const int rb_ = (wr * 32 + mi * 16 + m0) * 128;
      af[mi].h[0] = *(const i32x4*)&As[rb_ + cLo];
      af[mi].h[1] = *(const i32x4*)&As[rb_ + cHi];
    }
#pragma unroll
    for (int ni = 0; ni < 4; ni++) {
      const int rb_ = (wc * 64 + ni * 16 + m0) * 128;
      bf[ni].h[0] = *(const i32x4*)&Bs[rb_ + cLo];
      bf[ni].h[1] = *(const i32x4*)&Bs[rb_ + cHi];
    }
    // all of this wave's reads LANDED, then all waves passed -> safe to
    // overwrite the (single) buffer with the next tile
    asm volatile("s_waitcnt lgkmcnt(0)" ::: "memory");
    __builtin_amdgcn_s_barrier();
    if (kt < 4) STAGE_KT(kt + 1);

    __builtin_amdgcn_s_setprio(1);
#pragma unroll
    for (int mi = 0; mi < 2; mi++)
#pragma unroll
      for (int ni = 0; ni < 4; ni++)
        acc[mi][ni] = __builtin_amdgcn_mfma_scale_f32_16x16x128_f8f6f4(
            af[mi].v, bf[ni].v, acc[mi][ni],
            0 /*cbsz: A=fp8 e4m3*/, 0 /*blgp: B=fp8 e4m3*/,
            0, 0x7F7F7F7Fu /*scale A = 1.0*/,
            0, 0x7F7F7F7Fu /*scale B = 1.0*/);
    __builtin_amdgcn_s_setprio(0);

    if (kt < 4) {
      // next tile fully resident before any wave's next-iter ds_read
      asm volatile("s_waitcnt vmcnt(0)" ::: "memory");
      __builtin_amdgcn_s_barrier();
    }
  }
#undef STAGE_KT

  // epilogue: per-row max over this block's 128 columns, then global atomicMax
  // (C/D layout for 16x16 shapes: col = lane&15, row = (lane>>4)*4 + reg)
  const int colBase = bn * BN + wc * 64;
#pragma unroll
  for (int mi = 0; mi < 2; mi++) {
    float rmax[4] = {-3.0e38f, -3.0e38f, -3.0e38f, -3.0e38f};
#pragma unroll
    for (int ni = 0; ni < 4; ni++) {
      bool valid = (colBase + ni * 16 + m0) < N_REAL;
#pragma unroll
      for (int r = 0; r < 4; r++) {
        float v = valid ? acc[mi][ni][r] : -3.0e38f;
        rmax[r] = fmaxf(rmax[r], v);
      }
    }
#pragma unroll
    for (int r = 0; r < 4; r++) {
      float v = rmax[r];
      v = fmaxf(v, __shfl_xor(v, 1));
      v = fmaxf(v, __shfl_xor(v, 2));
      v = fmaxf(v, __shfl_xor(v, 4));
      v = fmaxf(v, __shfl_xor(v, 8));
      rmax[r] = v;
    }
    if (m0 == 0) {
      int row = bm * BM + wr * 32 + mi * 16 + q * 4;
#pragma unroll
      for (int r = 0; r < 4; r++)
        atomicMax(&rowmax[row + r], f2key(rmax[r]));
    }
  }
}

// =====================================================================
// Kernel C: fused tail — ONE kernel, 64 blocks (1 batch row each).
//   favg computed on the fly: mean over k of fa[k][:] (40 KB, L2).
// =====================================================================
__global__ __launch_bounds__(256) void tail_fused_kernel(
    const unsigned* __restrict__ rowmax, const float* __restrict__ qinv,
    const float* __restrict__ q_img, const float* __restrict__ fa,
    const float* __restrict__ hw1, const float* __restrict__ hb1,
    const float* __restrict__ hg2, const float* __restrict__ hbe2,
    const float* __restrict__ hw2, const float* __restrict__ hb2,
    const float* __restrict__ hg3, const float* __restrict__ hbe3,
    const float* __restrict__ hw3, const float* __restrict__ hb3,
    const float* __restrict__ rw1, const float* __restrict__ rb1,
    const float* __restrict__ rg2, const float* __restrict__ rbe2,
    const float* __restrict__ rw2, const float* __restrict__ rb2,
    const float* __restrict__ rg3, const float* __restrict__ rbe3,
    const float* __restrict__ rw3, const float* __restrict__ rb3,
    float* __restrict__ out) {
  __shared__ float A[240];    // amap row (225)
  __shared__ float R[640];    // res_img row
  __shared__ float P[256];    // GEMV1 partials
  __shared__ float Hr[128];   // ref hidden1 (post bn)
  __shared__ float Hm[128];   // map hidden1 (post bn)
  __shared__ float Q[256];    // layer2 partials (both heads)
  __shared__ float Hr2[64];   // ref hidden2
  __shared__ float Hm2[64];   // map hidden2
  __shared__ float red[16];   // [0..3] amean partials, [8]=s_ref, [9]=s_map

  const int b = blockIdx.x;
  const int tid = threadIdx.x;
  const int wave = tid >> 6, lane = tid & 63;

  // ---- amap row + amean partials; res row (favg on the fly) ----
  float am = 0.f;
  if (tid < P_DIM) {
    float mx = key2f(rowmax[b * P_DIM + tid]);
    float a = 0.5f * (1.f - mx * qinv[b * P_DIM + tid]);
    A[tid] = a;
    am = a;
  }
#pragma unroll
  for (int off = 32; off > 0; off >>= 1) am += __shfl_xor(am, off);
  if (lane == 0) red[wave] = am;
#pragma unroll
  for (int rep = 0; rep < 3; rep++) {
    int i = rep * 256 + tid;
    if (i < D_DIM) {
      float s = 0.f;
#pragma unroll
      for (int k = 0; k < 16; k++) s += fa[k * D_DIM + i];
      R[i] = q_img[b * D_DIM + i] - s * (1.f / 16.f);
    }
  }
  __syncthreads();

  const int j = tid & 127, bh = tid >> 7;

  // ---- s_ref GEMV1: 640 -> 128 (halved over bh) ----
  {
    float acc = bh ? 0.f : rb1[j];
    const int d0 = bh * 320;
#pragma unroll 8
    for (int d = 0; d < 320; d++) acc += R[d0 + d] * rw1[(d0 + d) * 128 + j];
    P[bh * 128 + j] = acc;
  }
  __syncthreads();
  if (tid < 128) Hr[tid] = fmaxf(P[tid] + P[128 + tid], 0.f) * rg2[tid] + rbe2[tid];
  __syncthreads();

  // ---- s_map GEMV1: 225 -> 128 (split 128/97 over bh) ----
  {
    float acc = bh ? 0.f : hb1[j];
    const int p0 = bh * 128;
    const int pn = bh ? (P_DIM - 128) : 128;
#pragma unroll 8
    for (int p = 0; p < pn; p++) acc += A[p0 + p] * hw1[(p0 + p) * 128 + j];
    P[bh * 128 + j] = acc;
  }
  __syncthreads();
  if (tid < 128) Hm[tid] = fmaxf(P[tid] + P[128 + tid], 0.f) * hg2[tid] + hbe2[tid];
  __syncthreads();

  // ---- layer2 both heads: 128 -> 64; g0/g1 = ref halves, g2/g3 = map ----
  {
    const int n = tid & 63, g = tid >> 6;
    const float* h = (g < 2) ? Hr : Hm;
    const float* w = (g < 2) ? rw2 : hw2;
    float acc = (g == 0) ? rb2[n] : (g == 2) ? hb2[n] : 0.f;
    const int j0 = (g & 1) * 64;
#pragma unroll 8
    for (int jj = 0; jj < 64; jj++) acc += h[j0 + jj] * w[(j0 + jj) * 64 + n];
    Q[g * 64 + n] = acc;
  }
  __syncthreads();
  if (tid < 64) Hr2[tid] = fmaxf(Q[tid] + Q[64 + tid], 0.f) * rg3[tid] + rbe3[tid];
  else if (tid < 128) {
    int n = tid - 64;
    Hm2[n] = fmaxf(Q[128 + n] + Q[192 + n], 0.f) * hg3[n] + hbe3[n];
  }
  __syncthreads();

  // ---- layer3 + sigmoid: wave 0 = ref, wave 1 = map ----
  if (wave == 0) {
    float v = Hr2[lane] * rw3[lane];
#pragma unroll
    for (int off = 32; off > 0; off >>= 1) v += __shfl_xor(v, off);
    if (lane == 0) red[8] = sigmoidf(v + rb3[0]);
  } else if (wave == 1) {
    float v = Hm2[lane] * hw3[lane];
#pragma unroll
    for (int off = 32; off > 0; off >>= 1) v += __shfl_xor(v, off);
    if (lane == 0) red[9] = sigmoidf(v + hb3[0]);
  }
  __syncthreads();

  if (tid == 0) {
    float amean = (red[0] + red[1] + red[2] + red[3]) * (1.f / 225.f);
    out[b] = 0.5f * (red[8] + red[9]) + amean;
  }
}

// ---------------- launch ----------------
extern "C" void kernel_launch(void* const* d_in, const int* in_sizes, int n_in,
                              void* d_out, int out_size, void* d_ws, size_t ws_size,
                              hipStream_t stream) {
  const float* q_patch = (const float*)d_in[0];
  const float* r_patch = (const float*)d_in[1];
  const float* q_img   = (const float*)d_in[2];
  const float* r_img   = (const float*)d_in[3];
  const float* adpt_w1 = (const float*)d_in[4];
  const float* adpt_w2 = (const float*)d_in[5];
  const float* dh_w1 = (const float*)d_in[6];
  const float* dh_b1 = (const float*)d_in[7];
  const float* dh_g2 = (const float*)d_in[8];
  const float* dh_be2 = (const float*)d_in[9];
  const float* dh_w2 = (const float*)d_in[10];
  const float* dh_b2 = (const float*)d_in[11];
  const float* dh_g3 = (const float*)d_in[12];
  const float* dh_be3 = (const float*)d_in[13];
  const float* dh_w3 = (const float*)d_in[14];
  const float* dh_b3 = (const float*)d_in[15];
  const float* dr_w1 = (const float*)d_in[16];
  const float* dr_b1 = (const float*)d_in[17];
  const float* dr_g2 = (const float*)d_in[18];
  const float* dr_be2 = (const float*)d_in[19];
  const float* dr_w2 = (const float*)d_in[20];
  const float* dr_b2 = (const float*)d_in[21];
  const float* dr_g3 = (const float*)d_in[22];
  const float* dr_be3 = (const float*)d_in[23];
  const float* dr_w3 = (const float*)d_in[24];
  const float* dr_b3 = (const float*)d_in[25];

  // ws layout (bytes) — fp8 staging buffers
  const size_t QB_BYTES = (size_t)MPAD * D_DIM;   // 9,256,960
  const size_t RB_BYTES = (size_t)NPAD * D_DIM;   // 2,375,680
  char* ws = (char*)d_ws;
  unsigned char* qb = (unsigned char*)(ws);
  unsigned char* rb = (unsigned char*)(ws + QB_BYTES);
  float* qinv        = (float*)(ws + QB_BYTES + RB_BYTES);
  unsigned* rowmax   = (unsigned*)(ws + QB_BYTES + RB_BYTES + (size_t)M_REAL * 4);
  float* fa          = (float*)(ws + QB_BYTES + RB_BYTES + (size_t)M_REAL * 4 + (size_t)MPAD * 4);

  stage_all_kernel<<<QBLKS + RBLKS, 256, 0, stream>>>(
      q_patch, r_patch, qb, rb, qinv, rowmax);
  sim_max_kernel<<<8 * MCHUNK * NTILES, 512, 0, stream>>>(
      qb, rb, rowmax, r_img, adpt_w1, adpt_w2, fa);
  tail_fused_kernel<<<B_DIM, 256, 0, stream>>>(
      rowmax, qinv, q_img, fa,
      dh_w1, dh_b1, dh_g2, dh_be2, dh_w2, dh_b2, dh_g3, dh_be3, dh_w3, dh_b3,
      dr_w1, dr_b1, dr_g2, dr_be2, dr_w2, dr_b2, dr_g3, dr_be3, dr_w3, dr_b3,
      (float*)d_out);
}